// Round 2
// baseline (564.399 us; speedup 1.0000x reference)
//
#include <hip/hip_runtime.h>

#define LORA_RANK 16
#define SCALING 2.0f

using bf16x8 = __attribute__((ext_vector_type(8))) __bf16;
using bf16x4 = __attribute__((ext_vector_type(4))) __bf16;
using f32x4  = __attribute__((ext_vector_type(4))) float;

#define GLB(p) ((const __attribute__((address_space(1))) void*)(p))
#define LDS(p) ((__attribute__((address_space(3))) void*)(p))

// ---------------------------------------------------------------------------
// Kernel 1: fold int8 dequant (arriving as int32) + LoRA into bf16 W[N][K].
// grid (K/256, N/64), block 256.
// ---------------------------------------------------------------------------
__global__ __launch_bounds__(256) void fold_weight_kernel(
    const int* __restrict__ q, const float* __restrict__ scales,
    const float* __restrict__ lA, const float* __restrict__ lB,
    __bf16* __restrict__ W, int N, int K)
{
    const int i0 = blockIdx.x * 256;
    const int o0 = blockIdx.y * 64;
    const int t  = threadIdx.x;

    __shared__ float As[LORA_RANK][256];
    __shared__ float Bs[64][LORA_RANK];

    #pragma unroll
    for (int j = 0; j < 16; ++j) {                 // 16*256 = 4096 lA floats
        int idx = t + j * 256;
        int r = idx >> 8, c = idx & 255;
        As[r][c] = lA[(long)r * K + i0 + c];
    }
    #pragma unroll
    for (int j = 0; j < 4; ++j) {                  // 64*16 = 1024 lB floats
        int idx = t + j * 256;
        int o = idx >> 4, r = idx & 15;
        Bs[o][r] = lB[(long)(o0 + o) * LORA_RANK + r] * SCALING;
    }
    __syncthreads();

    const int ol = t & 63;          // local output row
    const int iq = t >> 6;          // i-quarter
    const int o  = o0 + ol;
    const float sc = scales[o];

    float bb[LORA_RANK];
    #pragma unroll
    for (int r = 0; r < LORA_RANK; ++r) bb[r] = Bs[ol][r];

    const int* qrow = q + (long)o * K + i0 + iq * 64;
    __bf16*    wrow = W + (long)o * K + i0 + iq * 64;

    #pragma unroll
    for (int c = 0; c < 16; ++c) {                 // 16 iters * 4 elems = 64
        int4 q4 = *(const int4*)(qrow + c * 4);
        float v[4];
        v[0] = (float)q4.x * sc;
        v[1] = (float)q4.y * sc;
        v[2] = (float)q4.z * sc;
        v[3] = (float)q4.w * sc;
        const int ib = iq * 64 + c * 4;
        #pragma unroll
        for (int r = 0; r < LORA_RANK; ++r) {
            v[0] += bb[r] * As[r][ib + 0];
            v[1] += bb[r] * As[r][ib + 1];
            v[2] += bb[r] * As[r][ib + 2];
            v[3] += bb[r] * As[r][ib + 3];
        }
        bf16x4 wv;
        wv[0] = (__bf16)v[0]; wv[1] = (__bf16)v[1];
        wv[2] = (__bf16)v[2]; wv[3] = (__bf16)v[3];
        *(bf16x4*)(wrow + c * 4) = wv;
    }
}

// ---------------------------------------------------------------------------
// Kernel 2: C[M][N] = X[M][K](fp32->bf16) @ W[N][K]^T + bias.
// m97 structure: 128x128 tile, BK=32, 4 waves (2x2), 16x16x32 bf16 MFMA.
// ---------------------------------------------------------------------------
__global__ __launch_bounds__(256) void gemm_kernel(
    const float* __restrict__ X, const __bf16* __restrict__ W,
    const float* __restrict__ bias, float* __restrict__ C,
    int M, int N, int K)
{
    __shared__ __align__(16) __bf16 Asm[128][32];   // 8 KB
    __shared__ __align__(16) __bf16 Bsm[128][32];   // 8 KB

    const int nwg = gridDim.x;
    int bid = blockIdx.x;
    if ((nwg & 7) == 0) {                 // bijective XCD swizzle
        bid = (bid & 7) * (nwg >> 3) + (bid >> 3);
    }
    const int ntn = N >> 7;
    const int tm = bid / ntn, tn = bid % ntn;
    const int m0 = tm << 7, n0 = tn << 7;

    const int t    = threadIdx.x;
    const int wid  = t >> 6;
    const int lane = t & 63;
    const int wr = wid >> 1, wc = wid & 1;

    f32x4 acc[4][4] = {};

    // staging: thread t -> row = t>>2, 8-elem segment = t&3 (lane-linear LDS)
    const int srow = t >> 2, sseg = t & 3;
    const float*  Ag  = X + (long)(m0 + srow) * K + sseg * 8;
    const float*  Ag2 = X + (long)(m0 + 64 + srow) * K + sseg * 8;
    const __bf16* Bg  = W + (long)(n0 + srow) * K + sseg * 8;
    const __bf16* Bg2 = W + (long)(n0 + 64 + srow) * K + sseg * 8;

    // wave-uniform LDS dest bases (lane offset implicit x16B)
    __bf16* bs0 = &Bsm[0][0] + (wid * 64) * 8;
    __bf16* bs1 = &Bsm[0][0] + (256 + wid * 64) * 8;

    __bf16* aw0 = &Asm[srow][sseg * 8];
    __bf16* aw1 = &Asm[64 + srow][sseg * 8];

    const int frow = lane & 15;
    const int fk   = (lane >> 4) * 8;

    const int ksteps = K >> 5;
    for (int kt = 0; kt < ksteps; ++kt) {
        __builtin_amdgcn_global_load_lds(GLB(Bg),  LDS(bs0), 16, 0, 0);
        __builtin_amdgcn_global_load_lds(GLB(Bg2), LDS(bs1), 16, 0, 0);

        f32x4 a0 = *(const f32x4*)(Ag);
        f32x4 a1 = *(const f32x4*)(Ag + 4);
        f32x4 a2 = *(const f32x4*)(Ag2);
        f32x4 a3 = *(const f32x4*)(Ag2 + 4);
        bf16x8 av0, av1;
        #pragma unroll
        for (int j = 0; j < 4; ++j) {
            av0[j]     = (__bf16)a0[j];
            av0[j + 4] = (__bf16)a1[j];
            av1[j]     = (__bf16)a2[j];
            av1[j + 4] = (__bf16)a3[j];
        }
        *(bf16x8*)aw0 = av0;
        *(bf16x8*)aw1 = av1;

        Ag += 32; Ag2 += 32; Bg += 32; Bg2 += 32;

        __syncthreads();

        bf16x8 af[4], bfv[4];
        #pragma unroll
        for (int i = 0; i < 4; ++i) {
            af[i]  = *(const bf16x8*)&Asm[wr * 64 + i * 16 + frow][fk];
            bfv[i] = *(const bf16x8*)&Bsm[wc * 64 + i * 16 + frow][fk];
        }
        #pragma unroll
        for (int i = 0; i < 4; ++i)
            #pragma unroll
            for (int j = 0; j < 4; ++j)
                acc[i][j] = __builtin_amdgcn_mfma_f32_16x16x32_bf16(
                    af[i], bfv[j], acc[i][j], 0, 0, 0);

        __syncthreads();
    }

    // epilogue: C layout col = lane&15, row = (lane>>4)*4 + reg
    const int col0 = n0 + wc * 64 + (lane & 15);
    const int row0 = m0 + wr * 64 + (lane >> 4) * 4;
    #pragma unroll
    for (int j = 0; j < 4; ++j) {
        const int col = col0 + j * 16;
        const float bv = bias[col];
        #pragma unroll
        for (int i = 0; i < 4; ++i) {
            const int row = row0 + i * 16;
            #pragma unroll
            for (int e = 0; e < 4; ++e)
                C[(long)(row + e) * N + col] = acc[i][j][e] + bv;
        }
    }
}

// ---------------------------------------------------------------------------
// Fallback (only if ws too small): on-the-fly dequant+LoRA fp32 GEMM.
// ---------------------------------------------------------------------------
__global__ __launch_bounds__(256) void fallback_gemm(
    const float* __restrict__ X, const int* __restrict__ q,
    const float* __restrict__ scales, const float* __restrict__ bias,
    const float* __restrict__ lA, const float* __restrict__ lB,
    float* __restrict__ C, int M, int N, int K)
{
    __shared__ float Xs[64][17];
    __shared__ float Ws[64][17];
    __shared__ float At[LORA_RANK][16];
    __shared__ float Bt[64][LORA_RANK];

    const int ntn = N >> 6;
    const int m0 = (blockIdx.x / ntn) << 6, n0 = (blockIdx.x % ntn) << 6;
    const int t = threadIdx.x;

    for (int j = t; j < 64 * LORA_RANK; j += 256)
        Bt[j >> 4][j & 15] = lB[(long)(n0 + (j >> 4)) * LORA_RANK + (j & 15)] * SCALING;

    const int tr = (t & 15) * 4, tc = (t >> 4) * 4;
    float acc[4][4] = {};

    for (int k0 = 0; k0 < K; k0 += 16) {
        __syncthreads();
        for (int j = t; j < 1024; j += 256)
            Xs[j >> 4][j & 15] = X[(long)(m0 + (j >> 4)) * K + k0 + (j & 15)];
        At[t >> 4][t & 15] = lA[(long)(t >> 4) * K + k0 + (t & 15)];
        __syncthreads();
        for (int j = t; j < 1024; j += 256) {
            int o = j >> 4, kk = j & 15;
            float v = (float)q[(long)(n0 + o) * K + k0 + kk] * scales[n0 + o];
            #pragma unroll
            for (int r = 0; r < LORA_RANK; ++r) v += Bt[o][r] * At[r][kk];
            Ws[o][kk] = v;
        }
        __syncthreads();
        #pragma unroll 4
        for (int kk = 0; kk < 16; ++kk)
            #pragma unroll
            for (int i = 0; i < 4; ++i)
                #pragma unroll
                for (int j = 0; j < 4; ++j)
                    acc[i][j] += Xs[tr + i][kk] * Ws[tc + j][kk];
    }
    __syncthreads();
    #pragma unroll
    for (int i = 0; i < 4; ++i)
        #pragma unroll
        for (int j = 0; j < 4; ++j)
            C[(long)(m0 + tr + i) * N + n0 + tc + j] = acc[i][j] + bias[n0 + tc + j];
}

// ---------------------------------------------------------------------------
extern "C" void kernel_launch(void* const* d_in, const int* in_sizes, int n_in,
                              void* d_out, int out_size, void* d_ws, size_t ws_size,
                              hipStream_t stream)
{
    const float* x      = (const float*)d_in[0];
    const int*   qw     = (const int*)d_in[1];
    const float* scales = (const float*)d_in[2];
    const float* bias   = (const float*)d_in[3];
    const float* lA     = (const float*)d_in[4];
    const float* lB     = (const float*)d_in[5];
    float*       out    = (float*)d_out;

    const int K = in_sizes[4] / LORA_RANK;   // 4096
    const int N = in_sizes[2];               // 4096
    const int M = in_sizes[0] / K;           // 8192

    const size_t wbytes = (size_t)N * K * sizeof(__bf16);
    if (ws_size >= wbytes && (M % 128) == 0 && (N % 128) == 0 &&
        (K % 256) == 0 && (N % 64) == 0) {
        __bf16* W = (__bf16*)d_ws;
        dim3 g1(K / 256, N / 64);
        fold_weight_kernel<<<g1, 256, 0, stream>>>(qw, scales, lA, lB, W, N, K);
        const int nwg = (M / 128) * (N / 128);
        gemm_kernel<<<nwg, 256, 0, stream>>>(x, W, bias, out, M, N, K);
    } else {
        fallback_gemm<<<(M / 64) * (N / 64), 256, 0, stream>>>(
            x, qw, scales, bias, lA, lB, out, M, N, K);
    }
}

// Round 3
// 469.584 us; speedup vs baseline: 1.2019x; 1.2019x over previous
//
#include <hip/hip_runtime.h>

#define LORA_RANK 16
#define SCALING 2.0f

using bf16x8 = __attribute__((ext_vector_type(8))) __bf16;
using bf16x4 = __attribute__((ext_vector_type(4))) __bf16;
using f32x4  = __attribute__((ext_vector_type(4))) float;

#define GLB(p) ((const __attribute__((address_space(1))) void*)(p))
#define LDS(p) ((__attribute__((address_space(3))) void*)(p))

// ---------------------------------------------------------------------------
// Kernel 1: fold int8 dequant (arriving as int32) + LoRA into bf16 W[N][K].
// ---------------------------------------------------------------------------
__global__ __launch_bounds__(256) void fold_weight_kernel(
    const int* __restrict__ q, const float* __restrict__ scales,
    const float* __restrict__ lA, const float* __restrict__ lB,
    __bf16* __restrict__ W, int N, int K)
{
    const int i0 = blockIdx.x * 256;
    const int o0 = blockIdx.y * 64;
    const int t  = threadIdx.x;

    __shared__ float As[LORA_RANK][256];
    __shared__ float Bs[64][LORA_RANK];

    #pragma unroll
    for (int j = 0; j < 16; ++j) {
        int idx = t + j * 256;
        int r = idx >> 8, c = idx & 255;
        As[r][c] = lA[(long)r * K + i0 + c];
    }
    #pragma unroll
    for (int j = 0; j < 4; ++j) {
        int idx = t + j * 256;
        int o = idx >> 4, r = idx & 15;
        Bs[o][r] = lB[(long)(o0 + o) * LORA_RANK + r] * SCALING;
    }
    __syncthreads();

    const int ol = t & 63;
    const int iq = t >> 6;
    const int o  = o0 + ol;
    const float sc = scales[o];

    float bb[LORA_RANK];
    #pragma unroll
    for (int r = 0; r < LORA_RANK; ++r) bb[r] = Bs[ol][r];

    const int* qrow = q + (long)o * K + i0 + iq * 64;
    __bf16*    wrow = W + (long)o * K + i0 + iq * 64;

    #pragma unroll
    for (int c = 0; c < 16; ++c) {
        int4 q4 = *(const int4*)(qrow + c * 4);
        float v[4];
        v[0] = (float)q4.x * sc;
        v[1] = (float)q4.y * sc;
        v[2] = (float)q4.z * sc;
        v[3] = (float)q4.w * sc;
        const int ib = iq * 64 + c * 4;
        #pragma unroll
        for (int r = 0; r < LORA_RANK; ++r) {
            v[0] += bb[r] * As[r][ib + 0];
            v[1] += bb[r] * As[r][ib + 1];
            v[2] += bb[r] * As[r][ib + 2];
            v[3] += bb[r] * As[r][ib + 3];
        }
        bf16x4 wv;
        wv[0] = (__bf16)v[0]; wv[1] = (__bf16)v[1];
        wv[2] = (__bf16)v[2]; wv[3] = (__bf16)v[3];
        *(bf16x4*)(wrow + c * 4) = wv;
    }
}

// ---------------------------------------------------------------------------
// Kernel 1b: X fp32 -> bf16 (one pass, vectorized, grid-stride).
// ---------------------------------------------------------------------------
__global__ __launch_bounds__(256) void cvt_x_kernel(
    const float* __restrict__ X, __bf16* __restrict__ Xb, long n)
{
    const long stride = (long)gridDim.x * 256 * 8;
    for (long i = ((long)blockIdx.x * 256 + threadIdx.x) * 8; i < n; i += stride) {
        f32x4 a = *(const f32x4*)(X + i);
        f32x4 b = *(const f32x4*)(X + i + 4);
        bf16x8 v;
        #pragma unroll
        for (int j = 0; j < 4; ++j) {
            v[j]     = (__bf16)a[j];
            v[j + 4] = (__bf16)b[j];
        }
        *(bf16x8*)(Xb + i) = v;
    }
}

// ---------------------------------------------------------------------------
// Kernel 2: C[M][N] = Xb[M][K] @ W[N][K]^T + bias   (all-bf16, m97 structure)
// 128x128 tile, BK=32, 4 waves (2x2), all staging via global_load_lds w=16.
// ---------------------------------------------------------------------------
__global__ __launch_bounds__(256) void gemm_aa_kernel(
    const __bf16* __restrict__ Xb, const __bf16* __restrict__ W,
    const float* __restrict__ bias, float* __restrict__ C,
    int M, int N, int K)
{
    __shared__ __align__(16) __bf16 Asm[128][32];   // 8 KB
    __shared__ __align__(16) __bf16 Bsm[128][32];   // 8 KB

    const int nwg = gridDim.x;
    int bid = blockIdx.x;
    if ((nwg & 7) == 0) {                 // bijective XCD swizzle
        bid = (bid & 7) * (nwg >> 3) + (bid >> 3);
    }
    const int ntn = N >> 7;
    const int tm = bid / ntn, tn = bid % ntn;
    const int m0 = tm << 7, n0 = tn << 7;

    const int t    = threadIdx.x;
    const int wid  = t >> 6;
    const int lane = t & 63;
    const int wr = wid >> 1, wc = wid & 1;

    f32x4 acc[4][4] = {};

    // staging: thread t -> row = t>>2, 8-elem segment = t&3 (lane-linear LDS)
    const int srow = t >> 2, sseg = t & 3;
    const __bf16* Ag  = Xb + (long)(m0 + srow) * K + sseg * 8;
    const __bf16* Ag2 = Xb + (long)(m0 + 64 + srow) * K + sseg * 8;
    const __bf16* Bg  = W  + (long)(n0 + srow) * K + sseg * 8;
    const __bf16* Bg2 = W  + (long)(n0 + 64 + srow) * K + sseg * 8;

    // wave-uniform LDS dest bases (lane offset implicit x16B)
    __bf16* as0 = &Asm[0][0] + (wid * 64) * 8;
    __bf16* as1 = &Asm[0][0] + (256 + wid * 64) * 8;
    __bf16* bs0 = &Bsm[0][0] + (wid * 64) * 8;
    __bf16* bs1 = &Bsm[0][0] + (256 + wid * 64) * 8;

    const int frow = lane & 15;
    const int fk   = (lane >> 4) * 8;

    const int ksteps = K >> 5;
    for (int kt = 0; kt < ksteps; ++kt) {
        __builtin_amdgcn_global_load_lds(GLB(Ag),  LDS(as0), 16, 0, 0);
        __builtin_amdgcn_global_load_lds(GLB(Ag2), LDS(as1), 16, 0, 0);
        __builtin_amdgcn_global_load_lds(GLB(Bg),  LDS(bs0), 16, 0, 0);
        __builtin_amdgcn_global_load_lds(GLB(Bg2), LDS(bs1), 16, 0, 0);

        Ag += 32; Ag2 += 32; Bg += 32; Bg2 += 32;

        __syncthreads();

        bf16x8 af[4], bfv[4];
        #pragma unroll
        for (int i = 0; i < 4; ++i) {
            af[i]  = *(const bf16x8*)&Asm[wr * 64 + i * 16 + frow][fk];
            bfv[i] = *(const bf16x8*)&Bsm[wc * 64 + i * 16 + frow][fk];
        }
        #pragma unroll
        for (int i = 0; i < 4; ++i)
            #pragma unroll
            for (int j = 0; j < 4; ++j)
                acc[i][j] = __builtin_amdgcn_mfma_f32_16x16x32_bf16(
                    af[i], bfv[j], acc[i][j], 0, 0, 0);

        __syncthreads();
    }

    // epilogue: C layout col = lane&15, row = (lane>>4)*4 + reg
    const int col0 = n0 + wc * 64 + (lane & 15);
    const int row0 = m0 + wr * 64 + (lane >> 4) * 4;
    #pragma unroll
    for (int j = 0; j < 4; ++j) {
        const int col = col0 + j * 16;
        const float bv = bias[col];
        #pragma unroll
        for (int i = 0; i < 4; ++i) {
            const int row = row0 + i * 16;
            #pragma unroll
            for (int e = 0; e < 4; ++e)
                C[(long)(row + e) * N + col] = acc[i][j][e] + bv;
        }
    }
}

// ---------------------------------------------------------------------------
// Mid fallback: W in ws but no room for Xb — reg-stage A (round-2 kernel).
// ---------------------------------------------------------------------------
__global__ __launch_bounds__(256) void gemm_kernel(
    const float* __restrict__ X, const __bf16* __restrict__ W,
    const float* __restrict__ bias, float* __restrict__ C,
    int M, int N, int K)
{
    __shared__ __align__(16) __bf16 Asm[128][32];
    __shared__ __align__(16) __bf16 Bsm[128][32];

    const int nwg = gridDim.x;
    int bid = blockIdx.x;
    if ((nwg & 7) == 0) bid = (bid & 7) * (nwg >> 3) + (bid >> 3);
    const int ntn = N >> 7;
    const int tm = bid / ntn, tn = bid % ntn;
    const int m0 = tm << 7, n0 = tn << 7;

    const int t    = threadIdx.x;
    const int wid  = t >> 6;
    const int lane = t & 63;
    const int wr = wid >> 1, wc = wid & 1;

    f32x4 acc[4][4] = {};

    const int srow = t >> 2, sseg = t & 3;
    const float*  Ag  = X + (long)(m0 + srow) * K + sseg * 8;
    const float*  Ag2 = X + (long)(m0 + 64 + srow) * K + sseg * 8;
    const __bf16* Bg  = W + (long)(n0 + srow) * K + sseg * 8;
    const __bf16* Bg2 = W + (long)(n0 + 64 + srow) * K + sseg * 8;

    __bf16* bs0 = &Bsm[0][0] + (wid * 64) * 8;
    __bf16* bs1 = &Bsm[0][0] + (256 + wid * 64) * 8;
    __bf16* aw0 = &Asm[srow][sseg * 8];
    __bf16* aw1 = &Asm[64 + srow][sseg * 8];

    const int frow = lane & 15;
    const int fk   = (lane >> 4) * 8;

    const int ksteps = K >> 5;
    for (int kt = 0; kt < ksteps; ++kt) {
        __builtin_amdgcn_global_load_lds(GLB(Bg),  LDS(bs0), 16, 0, 0);
        __builtin_amdgcn_global_load_lds(GLB(Bg2), LDS(bs1), 16, 0, 0);

        f32x4 a0 = *(const f32x4*)(Ag);
        f32x4 a1 = *(const f32x4*)(Ag + 4);
        f32x4 a2 = *(const f32x4*)(Ag2);
        f32x4 a3 = *(const f32x4*)(Ag2 + 4);
        bf16x8 av0, av1;
        #pragma unroll
        for (int j = 0; j < 4; ++j) {
            av0[j]     = (__bf16)a0[j];
            av0[j + 4] = (__bf16)a1[j];
            av1[j]     = (__bf16)a2[j];
            av1[j + 4] = (__bf16)a3[j];
        }
        *(bf16x8*)aw0 = av0;
        *(bf16x8*)aw1 = av1;

        Ag += 32; Ag2 += 32; Bg += 32; Bg2 += 32;

        __syncthreads();

        bf16x8 af[4], bfv[4];
        #pragma unroll
        for (int i = 0; i < 4; ++i) {
            af[i]  = *(const bf16x8*)&Asm[wr * 64 + i * 16 + frow][fk];
            bfv[i] = *(const bf16x8*)&Bsm[wc * 64 + i * 16 + frow][fk];
        }
        #pragma unroll
        for (int i = 0; i < 4; ++i)
            #pragma unroll
            for (int j = 0; j < 4; ++j)
                acc[i][j] = __builtin_amdgcn_mfma_f32_16x16x32_bf16(
                    af[i], bfv[j], acc[i][j], 0, 0, 0);

        __syncthreads();
    }

    const int col0 = n0 + wc * 64 + (lane & 15);
    const int row0 = m0 + wr * 64 + (lane >> 4) * 4;
    #pragma unroll
    for (int j = 0; j < 4; ++j) {
        const int col = col0 + j * 16;
        const float bv = bias[col];
        #pragma unroll
        for (int i = 0; i < 4; ++i) {
            const int row = row0 + i * 16;
            #pragma unroll
            for (int e = 0; e < 4; ++e)
                C[(long)(row + e) * N + col] = acc[i][j][e] + bv;
        }
    }
}

// ---------------------------------------------------------------------------
// Last-resort fallback: on-the-fly dequant+LoRA fp32 GEMM (no ws).
// ---------------------------------------------------------------------------
__global__ __launch_bounds__(256) void fallback_gemm(
    const float* __restrict__ X, const int* __restrict__ q,
    const float* __restrict__ scales, const float* __restrict__ bias,
    const float* __restrict__ lA, const float* __restrict__ lB,
    float* __restrict__ C, int M, int N, int K)
{
    __shared__ float Xs[64][17];
    __shared__ float Ws[64][17];
    __shared__ float At[LORA_RANK][16];
    __shared__ float Bt[64][LORA_RANK];

    const int ntn = N >> 6;
    const int m0 = (blockIdx.x / ntn) << 6, n0 = (blockIdx.x % ntn) << 6;
    const int t = threadIdx.x;

    for (int j = t; j < 64 * LORA_RANK; j += 256)
        Bt[j >> 4][j & 15] = lB[(long)(n0 + (j >> 4)) * LORA_RANK + (j & 15)] * SCALING;

    const int tr = (t & 15) * 4, tc = (t >> 4) * 4;
    float acc[4][4] = {};

    for (int k0 = 0; k0 < K; k0 += 16) {
        __syncthreads();
        for (int j = t; j < 1024; j += 256)
            Xs[j >> 4][j & 15] = X[(long)(m0 + (j >> 4)) * K + k0 + (j & 15)];
        At[t >> 4][t & 15] = lA[(long)(t >> 4) * K + k0 + (t & 15)];
        __syncthreads();
        for (int j = t; j < 1024; j += 256) {
            int o = j >> 4, kk = j & 15;
            float v = (float)q[(long)(n0 + o) * K + k0 + kk] * scales[n0 + o];
            #pragma unroll
            for (int r = 0; r < LORA_RANK; ++r) v += Bt[o][r] * At[r][kk];
            Ws[o][kk] = v;
        }
        __syncthreads();
        #pragma unroll 4
        for (int kk = 0; kk < 16; ++kk)
            #pragma unroll
            for (int i = 0; i < 4; ++i)
                #pragma unroll
                for (int j = 0; j < 4; ++j)
                    acc[i][j] += Xs[tr + i][kk] * Ws[tc + j][kk];
    }
    __syncthreads();
    #pragma unroll
    for (int i = 0; i < 4; ++i)
        #pragma unroll
        for (int j = 0; j < 4; ++j)
            C[(long)(m0 + tr + i) * N + n0 + tc + j] = acc[i][j] + bias[n0 + tc + j];
}

// ---------------------------------------------------------------------------
extern "C" void kernel_launch(void* const* d_in, const int* in_sizes, int n_in,
                              void* d_out, int out_size, void* d_ws, size_t ws_size,
                              hipStream_t stream)
{
    const float* x      = (const float*)d_in[0];
    const int*   qw     = (const int*)d_in[1];
    const float* scales = (const float*)d_in[2];
    const float* bias   = (const float*)d_in[3];
    const float* lA     = (const float*)d_in[4];
    const float* lB     = (const float*)d_in[5];
    float*       out    = (float*)d_out;

    const int K = in_sizes[4] / LORA_RANK;   // 4096
    const int N = in_sizes[2];               // 4096
    const int M = in_sizes[0] / K;           // 8192

    const size_t wbytes = (size_t)N * K * sizeof(__bf16);
    const size_t xbytes = (size_t)M * K * sizeof(__bf16);
    const bool shape_ok = (M % 128) == 0 && (N % 128) == 0 &&
                          (K % 256) == 0 && (N % 64) == 0 && (M % 8) == 0;

    if (shape_ok && ws_size >= wbytes + xbytes) {
        __bf16* W  = (__bf16*)d_ws;
        __bf16* Xb = (__bf16*)((char*)d_ws + wbytes);
        dim3 g1(K / 256, N / 64);
        fold_weight_kernel<<<g1, 256, 0, stream>>>(qw, scales, lA, lB, W, N, K);
        cvt_x_kernel<<<2048, 256, 0, stream>>>(x, Xb, (long)M * K);
        const int nwg = (M / 128) * (N / 128);
        gemm_aa_kernel<<<nwg, 256, 0, stream>>>(Xb, W, bias, out, M, N, K);
    } else if (shape_ok && ws_size >= wbytes) {
        __bf16* W = (__bf16*)d_ws;
        dim3 g1(K / 256, N / 64);
        fold_weight_kernel<<<g1, 256, 0, stream>>>(qw, scales, lA, lB, W, N, K);
        const int nwg = (M / 128) * (N / 128);
        gemm_kernel<<<nwg, 256, 0, stream>>>(x, W, bias, out, M, N, K);
    } else {
        fallback_gemm<<<(M / 64) * (N / 64), 256, 0, stream>>>(
            x, qw, scales, bias, lA, lB, out, M, N, K);
    }
}

// Round 4
// 344.571 us; speedup vs baseline: 1.6380x; 1.3628x over previous
//
#include <hip/hip_runtime.h>

#define LORA_RANK 16
#define SCALING 2.0f

using bf16x8 = __attribute__((ext_vector_type(8))) __bf16;
using bf16x4 = __attribute__((ext_vector_type(4))) __bf16;
using f32x4  = __attribute__((ext_vector_type(4))) float;

#define GLB(p) ((const __attribute__((address_space(1))) void*)(p))
#define LDS(p) ((__attribute__((address_space(3))) void*)(p))

// ---------------------------------------------------------------------------
// Kernel 1: fold int8 dequant (arriving as int32) + LoRA into bf16 W[N][K].
// ---------------------------------------------------------------------------
__global__ __launch_bounds__(256) void fold_weight_kernel(
    const int* __restrict__ q, const float* __restrict__ scales,
    const float* __restrict__ lA, const float* __restrict__ lB,
    __bf16* __restrict__ W, int N, int K)
{
    const int i0 = blockIdx.x * 256;
    const int o0 = blockIdx.y * 64;
    const int t  = threadIdx.x;

    __shared__ float As[LORA_RANK][256];
    __shared__ float Bs[64][LORA_RANK];

    #pragma unroll
    for (int j = 0; j < 16; ++j) {
        int idx = t + j * 256;
        int r = idx >> 8, c = idx & 255;
        As[r][c] = lA[(long)r * K + i0 + c];
    }
    #pragma unroll
    for (int j = 0; j < 4; ++j) {
        int idx = t + j * 256;
        int o = idx >> 4, r = idx & 15;
        Bs[o][r] = lB[(long)(o0 + o) * LORA_RANK + r] * SCALING;
    }
    __syncthreads();

    const int ol = t & 63;
    const int iq = t >> 6;
    const int o  = o0 + ol;
    const float sc = scales[o];

    float bb[LORA_RANK];
    #pragma unroll
    for (int r = 0; r < LORA_RANK; ++r) bb[r] = Bs[ol][r];

    const int* qrow = q + (long)o * K + i0 + iq * 64;
    __bf16*    wrow = W + (long)o * K + i0 + iq * 64;

    #pragma unroll
    for (int c = 0; c < 16; ++c) {
        int4 q4 = *(const int4*)(qrow + c * 4);
        float v[4];
        v[0] = (float)q4.x * sc;
        v[1] = (float)q4.y * sc;
        v[2] = (float)q4.z * sc;
        v[3] = (float)q4.w * sc;
        const int ib = iq * 64 + c * 4;
        #pragma unroll
        for (int r = 0; r < LORA_RANK; ++r) {
            v[0] += bb[r] * As[r][ib + 0];
            v[1] += bb[r] * As[r][ib + 1];
            v[2] += bb[r] * As[r][ib + 2];
            v[3] += bb[r] * As[r][ib + 3];
        }
        bf16x4 wv;
        wv[0] = (__bf16)v[0]; wv[1] = (__bf16)v[1];
        wv[2] = (__bf16)v[2]; wv[3] = (__bf16)v[3];
        *(bf16x4*)(wrow + c * 4) = wv;
    }
}

// ---------------------------------------------------------------------------
// Kernel 1b: X fp32 -> bf16.
// ---------------------------------------------------------------------------
__global__ __launch_bounds__(256) void cvt_x_kernel(
    const float* __restrict__ X, __bf16* __restrict__ Xb, long n)
{
    const long stride = (long)gridDim.x * 256 * 8;
    for (long i = ((long)blockIdx.x * 256 + threadIdx.x) * 8; i < n; i += stride) {
        f32x4 a = *(const f32x4*)(X + i);
        f32x4 b = *(const f32x4*)(X + i + 4);
        bf16x8 v;
        #pragma unroll
        for (int j = 0; j < 4; ++j) {
            v[j]     = (__bf16)a[j];
            v[j + 4] = (__bf16)b[j];
        }
        *(bf16x8*)(Xb + i) = v;
    }
}

// ---------------------------------------------------------------------------
// Kernel 2: 256x256-tile 8-phase GEMM.  C[M][N] = Xb @ W^T + bias.
// 512 thr = 8 waves (2Mx4N); BK=64; dbuf LDS 128KiB; XOR-swizzled columns.
// ---------------------------------------------------------------------------
#define VMW   asm volatile("s_waitcnt vmcnt(0)" ::: "memory")
#define SB0   __builtin_amdgcn_sched_barrier(0)
#define NOPST ((void)0)

#define RD8(base, off) (*(const bf16x8*)((base) + (off)))

#define MFMA2(mi, nj, A0, A1, B0, B1) \
    acc[mi][nj] = __builtin_amdgcn_mfma_f32_16x16x32_bf16(A0, B0, acc[mi][nj], 0, 0, 0); \
    acc[mi][nj] = __builtin_amdgcn_mfma_f32_16x16x32_bf16(A1, B1, acc[mi][nj], 0, 0, 0);

// stage one 256x64 bf16 tile half-pair (A or B operand) into LDS region dst
#define STAGE_A(dst) do { \
    __builtin_amdgcn_global_load_lds(GLB(pA0),  LDS((dst) + wb),         16, 0, 0); \
    __builtin_amdgcn_global_load_lds(GLB(pA0b), LDS((dst) + wb +  8192), 16, 0, 0); \
    __builtin_amdgcn_global_load_lds(GLB(pA1),  LDS((dst) + wb + 16384), 16, 0, 0); \
    __builtin_amdgcn_global_load_lds(GLB(pA1b), LDS((dst) + wb + 24576), 16, 0, 0); \
    pA0 += 64; pA0b += 64; pA1 += 64; pA1b += 64; } while (0)

#define STAGE_B(dst) do { \
    __builtin_amdgcn_global_load_lds(GLB(pB0),  LDS((dst) + wb),         16, 0, 0); \
    __builtin_amdgcn_global_load_lds(GLB(pB0b), LDS((dst) + wb +  8192), 16, 0, 0); \
    __builtin_amdgcn_global_load_lds(GLB(pB1),  LDS((dst) + wb + 16384), 16, 0, 0); \
    __builtin_amdgcn_global_load_lds(GLB(pB1b), LDS((dst) + wb + 24576), 16, 0, 0); \
    pB0 += 64; pB0b += 64; pB1 += 64; pB1b += 64; } while (0)

// Two phases (qn=0,1) sharing the A-quadrant qm registers.
#define HALF(Ac, Bc, qm, S0, S1, W1, PB1) do { \
    const char* _ac = (Ac); const char* _bc = (Bc); \
    bf16x8 a0k0 = RD8(_ac, aRow + (qm)*8192 +    0 + kc0); \
    bf16x8 a1k0 = RD8(_ac, aRow + (qm)*8192 + 2048 + kc0); \
    bf16x8 a2k0 = RD8(_ac, aRow + (qm)*8192 + 4096 + kc0); \
    bf16x8 a3k0 = RD8(_ac, aRow + (qm)*8192 + 6144 + kc0); \
    bf16x8 a0k1 = RD8(_ac, aRow + (qm)*8192 +    0 + kc1); \
    bf16x8 a1k1 = RD8(_ac, aRow + (qm)*8192 + 2048 + kc1); \
    bf16x8 a2k1 = RD8(_ac, aRow + (qm)*8192 + 4096 + kc1); \
    bf16x8 a3k1 = RD8(_ac, aRow + (qm)*8192 + 6144 + kc1); \
    { bf16x8 b0k0 = RD8(_bc, bRow +    0 + kc0); \
      bf16x8 b1k0 = RD8(_bc, bRow + 2048 + kc0); \
      bf16x8 b0k1 = RD8(_bc, bRow +    0 + kc1); \
      bf16x8 b1k1 = RD8(_bc, bRow + 2048 + kc1); \
      S0; \
      __builtin_amdgcn_s_barrier(); \
      __builtin_amdgcn_s_setprio(1); \
      MFMA2((qm)*4+0, 0, a0k0, a0k1, b0k0, b0k1); \
      MFMA2((qm)*4+1, 0, a1k0, a1k1, b0k0, b0k1); \
      MFMA2((qm)*4+2, 0, a2k0, a2k1, b0k0, b0k1); \
      MFMA2((qm)*4+3, 0, a3k0, a3k1, b0k0, b0k1); \
      MFMA2((qm)*4+0, 1, a0k0, a0k1, b1k0, b1k1); \
      MFMA2((qm)*4+1, 1, a1k0, a1k1, b1k0, b1k1); \
      MFMA2((qm)*4+2, 1, a2k0, a2k1, b1k0, b1k1); \
      MFMA2((qm)*4+3, 1, a3k0, a3k1, b1k0, b1k1); \
      __builtin_amdgcn_s_setprio(0); \
      __builtin_amdgcn_s_barrier(); } \
    { bf16x8 b0k0 = RD8(_bc, bRow + 4096 +    0 + kc0); \
      bf16x8 b1k0 = RD8(_bc, bRow + 4096 + 2048 + kc0); \
      bf16x8 b0k1 = RD8(_bc, bRow + 4096 +    0 + kc1); \
      bf16x8 b1k1 = RD8(_bc, bRow + 4096 + 2048 + kc1); \
      S1; W1; \
      __builtin_amdgcn_s_barrier(); \
      PB1; \
      __builtin_amdgcn_s_setprio(1); \
      MFMA2((qm)*4+0, 2, a0k0, a0k1, b0k0, b0k1); \
      MFMA2((qm)*4+1, 2, a1k0, a1k1, b0k0, b0k1); \
      MFMA2((qm)*4+2, 2, a2k0, a2k1, b0k0, b0k1); \
      MFMA2((qm)*4+3, 2, a3k0, a3k1, b0k0, b0k1); \
      MFMA2((qm)*4+0, 3, a0k0, a0k1, b1k0, b1k1); \
      MFMA2((qm)*4+1, 3, a1k0, a1k1, b1k0, b1k1); \
      MFMA2((qm)*4+2, 3, a2k0, a2k1, b1k0, b1k1); \
      MFMA2((qm)*4+3, 3, a3k0, a3k1, b1k0, b1k1); \
      __builtin_amdgcn_s_setprio(0); \
      __builtin_amdgcn_s_barrier(); } \
  } while (0)

__global__ __launch_bounds__(512, 2) void gemm256_kernel(
    const __bf16* __restrict__ Xb, const __bf16* __restrict__ W,
    const float* __restrict__ bias, float* __restrict__ C,
    int M, int N, int K)
{
    // layout: buf0 A [0,32K) B [32K,64K) | buf1 A [64K,96K) B [96K,128K)
    __shared__ __align__(16) char smem[131072];

    const int t = threadIdx.x, wid = t >> 6, lane = t & 63;
    const int wr = wid >> 2, wc = wid & 3;
    const int l15 = lane & 15, l7 = lane & 7, lk = lane >> 4;

    const int nwg = gridDim.x;
    int bid = blockIdx.x;
    if ((nwg & 7) == 0) bid = (bid & 7) * (nwg >> 3) + (bid >> 3);
    const int ntn = N >> 8;
    const int m0 = (bid / ntn) << 8, n0 = (bid % ntn) << 8;

    // staging: thread t covers (row = t>>3, physchunk = t&7) + (row+64, same)
    // source chunk is XOR-preswizzled so linear LDS + swizzled reads agree.
    const int sr = t >> 3;
    const int sc = (t & 7) ^ (sr & 7);
    const __bf16* pA0  = Xb + (long)(m0 +       sr) * K + sc * 8;
    const __bf16* pA0b = Xb + (long)(m0 +  64 + sr) * K + sc * 8;
    const __bf16* pA1  = Xb + (long)(m0 + 128 + sr) * K + sc * 8;
    const __bf16* pA1b = Xb + (long)(m0 + 192 + sr) * K + sc * 8;
    const __bf16* pB0  = W  + (long)(n0 +       sr) * K + sc * 8;
    const __bf16* pB0b = W  + (long)(n0 +  64 + sr) * K + sc * 8;
    const __bf16* pB1  = W  + (long)(n0 + 128 + sr) * K + sc * 8;
    const __bf16* pB1b = W  + (long)(n0 + 192 + sr) * K + sc * 8;

    const int wb = wid * 1024;     // wave-uniform LDS stage base

    // fragment read offsets (XOR-swizzled chunk)
    const int aRow = (wr * 128 + l15) * 128;
    const int bRow = (wc * 64  + l15) * 128;
    const int kc0  = ((lk    ) ^ l7) << 4;
    const int kc1  = ((lk + 4) ^ l7) << 4;

    char* const bA0 = smem;
    char* const bB0 = smem + 32768;
    char* const bA1 = smem + 65536;
    char* const bB1 = smem + 98304;

    f32x4 acc[8][4] = {};

    // prologue: stage K-tile 0 into buf0
    STAGE_A(bA0);
    STAGE_B(bB0);
    VMW;
    __builtin_amdgcn_s_barrier();
    SB0;

    const int nkt = K >> 6;
    for (int kt = 0; kt < nkt; kt += 2) {
        const bool pf2 = (kt + 2 < nkt);
        // K-tile kt: compute from buf0, stage kt+1 into buf1
        HALF(bA0, bB0, 0, STAGE_A(bA1), STAGE_B(bB1), NOPST, NOPST);
        HALF(bA0, bB0, 1, NOPST, NOPST, VMW, SB0);
        // K-tile kt+1: compute from buf1, stage kt+2 into buf0
        HALF(bA1, bB1, 0, if (pf2) STAGE_A(bA0), if (pf2) STAGE_B(bB0), NOPST, NOPST);
        HALF(bA1, bB1, 1, NOPST, NOPST, VMW, SB0);
    }

    // epilogue: C layout col = lane&15, row = (lane>>4)*4 + e
    #pragma unroll
    for (int nj = 0; nj < 4; ++nj) {
        const int col = n0 + wc * 64 + nj * 16 + l15;
        const float bv = bias[col];
        #pragma unroll
        for (int mi = 0; mi < 8; ++mi) {
            const long row = (long)m0 + wr * 128 + mi * 16 + (lane >> 4) * 4;
            float* Cp = C + row * N + col;
            Cp[0]         = acc[mi][nj][0] + bv;
            Cp[(long)N]   = acc[mi][nj][1] + bv;
            Cp[2L * N]    = acc[mi][nj][2] + bv;
            Cp[3L * N]    = acc[mi][nj][3] + bv;
        }
    }
}

// ---------------------------------------------------------------------------
// Fallback: 128x128 m97-structure GEMM (round-3 kernel, for odd shapes).
// ---------------------------------------------------------------------------
__global__ __launch_bounds__(256) void gemm_aa_kernel(
    const __bf16* __restrict__ Xb, const __bf16* __restrict__ W,
    const float* __restrict__ bias, float* __restrict__ C,
    int M, int N, int K)
{
    __shared__ __align__(16) __bf16 Asm[128][32];
    __shared__ __align__(16) __bf16 Bsm[128][32];

    const int nwg = gridDim.x;
    int bid = blockIdx.x;
    if ((nwg & 7) == 0) bid = (bid & 7) * (nwg >> 3) + (bid >> 3);
    const int ntn = N >> 7;
    const int tm = bid / ntn, tn = bid % ntn;
    const int m0 = tm << 7, n0 = tn << 7;

    const int t    = threadIdx.x;
    const int wid  = t >> 6;
    const int lane = t & 63;
    const int wr = wid >> 1, wc = wid & 1;

    f32x4 acc[4][4] = {};

    const int srow = t >> 2, sseg = t & 3;
    const __bf16* Ag  = Xb + (long)(m0 + srow) * K + sseg * 8;
    const __bf16* Ag2 = Xb + (long)(m0 + 64 + srow) * K + sseg * 8;
    const __bf16* Bg  = W  + (long)(n0 + srow) * K + sseg * 8;
    const __bf16* Bg2 = W  + (long)(n0 + 64 + srow) * K + sseg * 8;

    __bf16* as0 = &Asm[0][0] + (wid * 64) * 8;
    __bf16* as1 = &Asm[0][0] + (256 + wid * 64) * 8;
    __bf16* bs0 = &Bsm[0][0] + (wid * 64) * 8;
    __bf16* bs1 = &Bsm[0][0] + (256 + wid * 64) * 8;

    const int frow = lane & 15;
    const int fk   = (lane >> 4) * 8;

    const int ksteps = K >> 5;
    for (int kt = 0; kt < ksteps; ++kt) {
        __builtin_amdgcn_global_load_lds(GLB(Ag),  LDS(as0), 16, 0, 0);
        __builtin_amdgcn_global_load_lds(GLB(Ag2), LDS(as1), 16, 0, 0);
        __builtin_amdgcn_global_load_lds(GLB(Bg),  LDS(bs0), 16, 0, 0);
        __builtin_amdgcn_global_load_lds(GLB(Bg2), LDS(bs1), 16, 0, 0);

        Ag += 32; Ag2 += 32; Bg += 32; Bg2 += 32;

        __syncthreads();

        bf16x8 af[4], bfv[4];
        #pragma unroll
        for (int i = 0; i < 4; ++i) {
            af[i]  = *(const bf16x8*)&Asm[wr * 64 + i * 16 + frow][fk];
            bfv[i] = *(const bf16x8*)&Bsm[wc * 64 + i * 16 + frow][fk];
        }
        #pragma unroll
        for (int i = 0; i < 4; ++i)
            #pragma unroll
            for (int j = 0; j < 4; ++j)
                acc[i][j] = __builtin_amdgcn_mfma_f32_16x16x32_bf16(
                    af[i], bfv[j], acc[i][j], 0, 0, 0);

        __syncthreads();
    }

    const int col0 = n0 + wc * 64 + (lane & 15);
    const int row0 = m0 + wr * 64 + (lane >> 4) * 4;
    #pragma unroll
    for (int j = 0; j < 4; ++j) {
        const int col = col0 + j * 16;
        const float bv = bias[col];
        #pragma unroll
        for (int i = 0; i < 4; ++i) {
            const int row = row0 + i * 16;
            #pragma unroll
            for (int e = 0; e < 4; ++e)
                C[(long)(row + e) * N + col] = acc[i][j][e] + bv;
        }
    }
}

// ---------------------------------------------------------------------------
// Last-resort fallback: on-the-fly dequant+LoRA fp32 GEMM (no ws).
// ---------------------------------------------------------------------------
__global__ __launch_bounds__(256) void fallback_gemm(
    const float* __restrict__ X, const int* __restrict__ q,
    const float* __restrict__ scales, const float* __restrict__ bias,
    const float* __restrict__ lA, const float* __restrict__ lB,
    float* __restrict__ C, int M, int N, int K)
{
    __shared__ float Xs[64][17];
    __shared__ float Ws[64][17];
    __shared__ float At[LORA_RANK][16];
    __shared__ float Bt[64][LORA_RANK];

    const int ntn = N >> 6;
    const int m0 = (blockIdx.x / ntn) << 6, n0 = (blockIdx.x % ntn) << 6;
    const int t = threadIdx.x;

    for (int j = t; j < 64 * LORA_RANK; j += 256)
        Bt[j >> 4][j & 15] = lB[(long)(n0 + (j >> 4)) * LORA_RANK + (j & 15)] * SCALING;

    const int tr = (t & 15) * 4, tc = (t >> 4) * 4;
    float acc[4][4] = {};

    for (int k0 = 0; k0 < K; k0 += 16) {
        __syncthreads();
        for (int j = t; j < 1024; j += 256)
            Xs[j >> 4][j & 15] = X[(long)(m0 + (j >> 4)) * K + k0 + (j & 15)];
        At[t >> 4][t & 15] = lA[(long)(t >> 4) * K + k0 + (t & 15)];
        __syncthreads();
        for (int j = t; j < 1024; j += 256) {
            int o = j >> 4, kk = j & 15;
            float v = (float)q[(long)(n0 + o) * K + k0 + kk] * scales[n0 + o];
            #pragma unroll
            for (int r = 0; r < LORA_RANK; ++r) v += Bt[o][r] * At[r][kk];
            Ws[o][kk] = v;
        }
        __syncthreads();
        #pragma unroll 4
        for (int kk = 0; kk < 16; ++kk)
            #pragma unroll
            for (int i = 0; i < 4; ++i)
                #pragma unroll
                for (int j = 0; j < 4; ++j)
                    acc[i][j] += Xs[tr + i][kk] * Ws[tc + j][kk];
    }
    __syncthreads();
    #pragma unroll
    for (int i = 0; i < 4; ++i)
        #pragma unroll
        for (int j = 0; j < 4; ++j)
            C[(long)(m0 + tr + i) * N + n0 + tc + j] = acc[i][j] + bias[n0 + tc + j];
}

// ---------------------------------------------------------------------------
extern "C" void kernel_launch(void* const* d_in, const int* in_sizes, int n_in,
                              void* d_out, int out_size, void* d_ws, size_t ws_size,
                              hipStream_t stream)
{
    const float* x      = (const float*)d_in[0];
    const int*   qw     = (const int*)d_in[1];
    const float* scales = (const float*)d_in[2];
    const float* bias   = (const float*)d_in[3];
    const float* lA     = (const float*)d_in[4];
    const float* lB     = (const float*)d_in[5];
    float*       out    = (float*)d_out;

    const int K = in_sizes[4] / LORA_RANK;   // 4096
    const int N = in_sizes[2];               // 4096
    const int M = in_sizes[0] / K;           // 8192

    const size_t wbytes = (size_t)N * K * sizeof(__bf16);
    const size_t xbytes = (size_t)M * K * sizeof(__bf16);
    const bool big_ok = (M % 256) == 0 && (N % 256) == 0 && (K % 128) == 0 &&
                        (K % 256) == 0;     // K%256 for fold grid
    const bool shape_ok = (M % 128) == 0 && (N % 128) == 0 && (K % 256) == 0;

    if (big_ok && ws_size >= wbytes + xbytes) {
        __bf16* W  = (__bf16*)d_ws;
        __bf16* Xb = (__bf16*)((char*)d_ws + wbytes);
        dim3 g1(K / 256, N / 64);
        fold_weight_kernel<<<g1, 256, 0, stream>>>(qw, scales, lA, lB, W, N, K);
        cvt_x_kernel<<<2048, 256, 0, stream>>>(x, Xb, (long)M * K);
        const int nwg = (M / 256) * (N / 256);
        gemm256_kernel<<<nwg, 512, 0, stream>>>(Xb, W, bias, out, M, N, K);
    } else if (shape_ok && ws_size >= wbytes + xbytes) {
        __bf16* W  = (__bf16*)d_ws;
        __bf16* Xb = (__bf16*)((char*)d_ws + wbytes);
        dim3 g1(K / 256, N / 64);
        fold_weight_kernel<<<g1, 256, 0, stream>>>(qw, scales, lA, lB, W, N, K);
        cvt_x_kernel<<<2048, 256, 0, stream>>>(x, Xb, (long)M * K);
        const int nwg = (M / 128) * (N / 128);
        gemm_aa_kernel<<<nwg, 256, 0, stream>>>(Xb, W, bias, out, M, N, K);
    } else {
        fallback_gemm<<<(M / 64) * (N / 64), 256, 0, stream>>>(
            x, qw, scales, bias, lA, lB, out, M, N, K);
    }
}